// Round 3
// baseline (432.950 us; speedup 1.0000x reference)
//
#include <hip/hip_runtime.h>

#define T_ 12
#define N_ 1370
#define NBLK 1370   // 87680 seqs / 64 per block

typedef __attribute__((ext_vector_type(4))) short short4v;
typedef __attribute__((ext_vector_type(8))) short short8;
typedef __attribute__((ext_vector_type(4))) float floatx4;
typedef __attribute__((ext_vector_type(2))) unsigned uint2v;
typedef __attribute__((ext_vector_type(4))) unsigned uint4v;

#define NLOG2E -1.4426950408889634f
#define TLOG2E 2.8853900817779268f
#define N2LOG2E -5.7707801635558536f   // -2*TLOG2E

__device__ __forceinline__ short f2bf(float x) {
  unsigned u = __builtin_bit_cast(unsigned, x);
  u = (u + 0x7fffu + ((u >> 16) & 1u)) >> 16;
  return (short)u;
}
// HW packed f32->bf16 (RNE): low16 = bf16(a), high16 = bf16(b)
__device__ __forceinline__ unsigned pk_bf16(float a, float b) {
  unsigned r;
  asm("v_cvt_pk_bf16_f32 %0, %1, %2" : "=v"(r) : "v"(a), "v"(b));
  return r;
}
// float4 -> 2 packed bf16 words, scaled
__device__ __forceinline__ uint2v cvt4(const float* __restrict__ p, float s) {
  floatx4 v = *(const floatx4*)p;
  uint2v r = {pk_bf16(v[0] * s, v[1] * s), pk_bf16(v[2] * s, v[3] * s)};
  return r;
}
__device__ __forceinline__ short4v mk4(unsigned lo, unsigned hi) {
  uint2v u = {lo, hi};
  return __builtin_bit_cast(short4v, u);
}
__device__ __forceinline__ short4v lo4(short8 v) {
  return __builtin_shufflevector(v, v, 0, 1, 2, 3);
}
__device__ __forceinline__ short4v hi4(short8 v) {
  return __builtin_shufflevector(v, v, 4, 5, 6, 7);
}

__device__ __forceinline__ floatx4 mfma16(short4v a, short4v b, floatx4 c) {
#if __has_builtin(__builtin_amdgcn_mfma_f32_16x16x16bf16_1k)
  return __builtin_amdgcn_mfma_f32_16x16x16bf16_1k(a, b, c, 0, 0, 0);
#elif __has_builtin(__builtin_amdgcn_mfma_f32_16x16x16_bf16)
  return __builtin_amdgcn_mfma_f32_16x16x16_bf16(a, b, c, 0, 0, 0);
#else
  asm volatile("v_mfma_f32_16x16x16_bf16 %0, %1, %2, %0\n\ts_nop 7\n\ts_nop 7"
               : "+v"(c)
               : "v"(a), "v"(b));
  return c;
#endif
}

// k=16 MFMA LSTM: the D-fragment of unit-tile ut (lane q,m16 holds
// h[seq=m16][ut*16+q*4+r]) IS the B-fragment of k-chunk ut for the next
// timestep (B[k=4q+j][n=m16] = h[m16][kc*16+4q+j]) -- the recurrence stays
// in registers; no LDS h traffic, no cross-lane, no barriers in the t-loop.
// Each wave: 16 seqs (n=m16), all 64 units (4 ut-tiles), 4 gates,
// k-chunks 0..3 = h, chunk 4 = [x(8) | bias=1 | 0...] at k=64..79.
// A = weights from LDS: whl pairs two k-chunks per ds_read_b128; wxl holds
// the x/bias A-frags (q0: W_ih cols 0-3, q1: cols 4-7, q2 j0: scaled bias).
// Activation scales pre-folded: i,f,o rows by -log2e, g rows by 2*log2e;
// cell state carried pre-scaled by 2*log2e (proven numerics from R0-R2).
__global__ void __launch_bounds__(256, 4) lstm_kernel(
    const float* __restrict__ x, const float* __restrict__ W_ih,
    const float* __restrict__ W_hh, const float* __restrict__ b_ih,
    const float* __restrict__ b_hh, const float* __restrict__ W_fc,
    const float* __restrict__ b_fc, float* __restrict__ out) {
  __shared__ short8 whl[32][64];    // [(g*4+ut)*2+kc2][lane]  32 KB
  __shared__ short4v wxl[16][64];   // [g*4+ut][lane]           8 KB

  const int tid = threadIdx.x;
  const int wave = tid >> 6;
  const int lane = tid & 63;
  const int m16 = lane & 15;
  const int q = lane >> 4;
  const int blk = blockIdx.x;

  // ---- cooperative weight staging: 2048 whl slots + 1024 wxl slots ----
#pragma unroll
  for (int p = 0; p < 8; ++p) {
    const int s = p * 256 + tid;
    const int l = s & 63, f = s >> 6;          // f = (g*4+ut)*2+kc2
    const int g = f >> 3, ut = (f >> 1) & 3, kc2 = f & 1;
    const float sg = (g == 2) ? TLOG2E : NLOG2E;
    const int md = l & 15, qd = l >> 4;
    const float* wr = W_hh + (g * 64 + ut * 16 + md) * 64 + kc2 * 32 + qd * 4;
    uint2v w0 = cvt4(wr, sg);        // k-chunk 2*kc2,   j=0..3
    uint2v w1 = cvt4(wr + 16, sg);   // k-chunk 2*kc2+1, j=0..3
    uint4v u = {w0.x, w0.y, w1.x, w1.y};
    whl[f][l] = __builtin_bit_cast(short8, u);
  }
#pragma unroll
  for (int p = 0; p < 4; ++p) {
    const int s = p * 256 + tid;
    const int l = s & 63, f = s >> 6;          // f = g*4+ut
    const int g = f >> 2, ut = f & 3;
    const float sg = (g == 2) ? TLOG2E : NLOG2E;
    const int md = l & 15, qd = l >> 4;
    const int grow = g * 64 + ut * 16 + md;
    uint2v w = {0u, 0u};
    if (qd < 2) {
      w = cvt4(W_ih + grow * 8 + qd * 4, sg);              // x columns
    } else if (qd == 2) {
      w.x = (unsigned)(unsigned short)f2bf(sg * (b_ih[grow] + b_hh[grow]));
    }
    wxl[f][l] = __builtin_bit_cast(short4v, w);
  }
  __syncthreads();   // the ONLY barrier

  // ---- x pointers: lane (q<2, m16) loads 16B of seq m16's x per t ----
  const int seq = blk * 64 + wave * 16 + m16;
  const int bidx = seq / N_;
  const int nidx = seq - bidx * N_;
  const float* xptr = x + ((size_t)(bidx * T_) * N_ + nidx) * 8 + q * 4;
  const size_t xstride = (size_t)N_ * 8;

  floatx4 cx = {0.0f, 0.0f, 0.0f, 0.0f};
  if (q < 2) cx = *(const floatx4*)xptr;

  const floatx4 zacc = {0.0f, 0.0f, 0.0f, 0.0f};
  short4v hA[4];   // h B-frags, k-chunk = ut
#pragma unroll
  for (int kc = 0; kc < 4; ++kc) hA[kc] = mk4(0u, 0u);

  float cst[4][4];
#pragma unroll
  for (int ut = 0; ut < 4; ++ut)
#pragma unroll
    for (int r = 0; r < 4; ++r) cst[ut][r] = 0.0f;

#pragma unroll 2
  for (int t = 0; t < T_; ++t) {
    // B x-chunk: q0/q1 = x bf16, q2 = {1.0,0,0,0} (bias col), q3 = 0
    uint2v xw = {pk_bf16(cx[0], cx[1]), pk_bf16(cx[2], cx[3])};
    if (q == 2) xw.x = 0x00003F80u;            // q>=2: cx==0 -> rest zero
    const short4v xB = __builtin_bit_cast(short4v, xw);
    // prefetch next t's x (hidden under this t's compute)
    floatx4 nx = {0.0f, 0.0f, 0.0f, 0.0f};
    if (t + 1 < T_ && q < 2)
      nx = *(const floatx4*)(xptr + (size_t)(t + 1) * xstride);

    short4v hN[4];
#pragma unroll
    for (int ut = 0; ut < 4; ++ut) {
      floatx4 acc[4];
#pragma unroll
      for (int g = 0; g < 4; ++g) {
        const short8 pA = whl[(g * 4 + ut) * 2 + 0][lane];
        const short8 pB = whl[(g * 4 + ut) * 2 + 1][lane];
        const short4v ax = wxl[g * 4 + ut][lane];
        floatx4 c = mfma16(lo4(pA), hA[0], zacc);
        c = mfma16(hi4(pA), hA[1], c);
        c = mfma16(lo4(pB), hA[2], c);
        c = mfma16(hi4(pB), hA[3], c);
        c = mfma16(ax, xB, c);
        acc[g] = c;
      }
      float hv[4];
#pragma unroll
      for (int r = 0; r < 4; ++r) {
        float di = 1.0f + __builtin_amdgcn_exp2f(acc[0][r]);
        float df = 1.0f + __builtin_amdgcn_exp2f(acc[1][r]);
        float dg = 1.0f + __builtin_amdgcn_exp2f(acc[2][r]);
        float dq = 1.0f + __builtin_amdgcn_exp2f(acc[3][r]);
        float pa = di * df, pb = dg * dq;
        float rp = __builtin_amdgcn_rcpf(pa * pb);
        float fv = rp * di * pb;                       // f = 1/df
        float ov = rp * pa * dg;                       // o = 1/dq
        float tg = fmaf(TLOG2E, dg, N2LOG2E);          // (dg-2)*2log2e
        float ig = tg * rp * (df * dq);                // i*g*2log2e
        float cs = fmaf(fv, cst[ut][r], ig);           // c*2log2e
        cst[ut][r] = cs;
        float dt = 1.0f + __builtin_amdgcn_exp2f(cs);
        float tc = fmaf(-2.0f, __builtin_amdgcn_rcpf(dt), 1.0f);  // tanh(c)
        hv[r] = ov * tc;
      }
      // D pairs ARE next-t B-frag chunk ut: {(hv0,hv1),(hv2,hv3)}
      hN[ut] = mk4(pk_bf16(hv[0], hv[1]), pk_bf16(hv[2], hv[3]));
    }
#pragma unroll
    for (int kc = 0; kc < 4; ++kc) hA[kc] = hN[kc];
    cx = nx;
  }

  // ---- final FC: y = h_T @ W_fc^T + b_fc; h_T = hA, in registers ----
  {
    short4v fcA[4];
#pragma unroll
    for (int kc = 0; kc < 4; ++kc) {
      uint2v w = {0u, 0u};
      if (m16 < 8) w = cvt4(W_fc + m16 * 64 + kc * 16 + q * 4, 1.0f);
      fcA[kc] = __builtin_bit_cast(short4v, w);
    }
    floatx4 acc = zacc;
#pragma unroll
    for (int kc = 0; kc < 4; ++kc) acc = mfma16(fcA[kc], hA[kc], acc);
    if (q < 2) {
      const int orow = blk * 64 + wave * 16 + m16;
#pragma unroll
      for (int r = 0; r < 4; ++r)
        out[orow * 8 + q * 4 + r] = acc[r] + b_fc[q * 4 + r];
    }
  }
}

extern "C" void kernel_launch(void* const* d_in, const int* in_sizes, int n_in,
                              void* d_out, int out_size, void* d_ws,
                              size_t ws_size, hipStream_t stream) {
  const float* x    = (const float*)d_in[0];
  const float* W_ih = (const float*)d_in[1];
  const float* W_hh = (const float*)d_in[2];
  const float* b_ih = (const float*)d_in[3];
  const float* b_hh = (const float*)d_in[4];
  const float* W_fc = (const float*)d_in[5];
  const float* b_fc = (const float*)d_in[6];
  float* out = (float*)d_out;
  hipLaunchKernelGGL(lstm_kernel, dim3(NBLK), dim3(256), 0, stream,
                     x, W_ih, W_hh, b_ih, b_hh, W_fc, b_fc, out);
}

// Round 6
// 211.366 us; speedup vs baseline: 2.0483x; 2.0483x over previous
//
#include <hip/hip_runtime.h>

#define T_ 12
#define N_ 1370
#define NBLK 1370   // 87680 seqs / 64 per block

typedef __attribute__((ext_vector_type(4))) short short4v;
typedef __attribute__((ext_vector_type(8))) short short8;
typedef __attribute__((ext_vector_type(4))) float floatx4;
typedef __attribute__((ext_vector_type(2))) unsigned uint2v;
typedef __attribute__((ext_vector_type(4))) unsigned uint4v;

#define NLOG2E -1.4426950408889634f
#define TLOG2E 2.8853900817779268f
#define N2LOG2E -5.7707801635558536f   // -2*TLOG2E

__device__ __forceinline__ short f2bf(float x) {
  unsigned u = __builtin_bit_cast(unsigned, x);
  u = (u + 0x7fffu + ((u >> 16) & 1u)) >> 16;
  return (short)u;
}
// HW packed f32->bf16 (RNE): low16 = bf16(a), high16 = bf16(b)
__device__ __forceinline__ unsigned pk_bf16(float a, float b) {
  unsigned r;
  asm("v_cvt_pk_bf16_f32 %0, %1, %2" : "=v"(r) : "v"(a), "v"(b));
  return r;
}
// float4 -> 2 packed bf16 words, scaled
__device__ __forceinline__ uint2v cvt4(const float* __restrict__ p, float s) {
  floatx4 v = *(const floatx4*)p;
  uint2v r = {pk_bf16(v[0] * s, v[1] * s), pk_bf16(v[2] * s, v[3] * s)};
  return r;
}
__device__ __forceinline__ short4v mk4(unsigned lo, unsigned hi) {
  uint2v u = {lo, hi};
  return __builtin_bit_cast(short4v, u);
}
__device__ __forceinline__ short4v lo4(short8 v) {
  return __builtin_shufflevector(v, v, 0, 1, 2, 3);
}
__device__ __forceinline__ short4v hi4(short8 v) {
  return __builtin_shufflevector(v, v, 4, 5, 6, 7);
}

__device__ __forceinline__ floatx4 mfma16(short4v a, short4v b, floatx4 c) {
#if __has_builtin(__builtin_amdgcn_mfma_f32_16x16x16bf16_1k)
  return __builtin_amdgcn_mfma_f32_16x16x16bf16_1k(a, b, c, 0, 0, 0);
#elif __has_builtin(__builtin_amdgcn_mfma_f32_16x16x16_bf16)
  return __builtin_amdgcn_mfma_f32_16x16x16_bf16(a, b, c, 0, 0, 0);
#else
  asm volatile("v_mfma_f32_16x16x16_bf16 %0, %1, %2, %0\n\ts_nop 7\n\ts_nop 7"
               : "+v"(c)
               : "v"(a), "v"(b));
  return c;
#endif
}

// k=16 register-recurrence LSTM -- EXACTLY the R3 kernel (passed, layouts
// HW-verified) with ONE change: the whl/wxl base pointers are laundered
// through an empty asm at the top of every t-iteration. This makes them
// loop-variant to the compiler, so LICM cannot hoist the 48 loop-invariant
// weight fragments into registers -- which under the (256,4) 128-VGPR cap
// is what produced R3's 1.2 GB/dispatch scratch traffic (378 us). Weights
// are re-read from LDS each timestep (conflict-free b128/b64, ~48 reads/t),
// live set ~100 VGPR, no spill, 4 blocks/CU.
// Recurrence: D-fragment of unit-tile ut (lane(q,m16) reg r =
// h[seq=m16][ut*16+q*4+r]) IS the next-t B-fragment of k-chunk ut
// (B[k=4q+j][n=m16]); h never leaves the lane, no t-loop barriers.
// Activation scales pre-folded: i,f,o rows by -log2e, g rows by 2*log2e;
// cell state carried pre-scaled by 2*log2e. (Numerics verified R0-R3.)
__global__ void __launch_bounds__(256, 4) lstm_kernel(
    const float* __restrict__ x, const float* __restrict__ W_ih,
    const float* __restrict__ W_hh, const float* __restrict__ b_ih,
    const float* __restrict__ b_hh, const float* __restrict__ W_fc,
    const float* __restrict__ b_fc, float* __restrict__ out) {
  __shared__ short8 whl[32][64];    // [(g*4+ut)*2+kc2][lane]  32 KB
  __shared__ short4v wxl[16][64];   // [g*4+ut][lane]           8 KB

  const int tid = threadIdx.x;
  const int wave = tid >> 6;
  const int lane = tid & 63;
  const int m16 = lane & 15;
  const int q = lane >> 4;
  const int blk = blockIdx.x;

  // ---- cooperative weight staging: 2048 whl slots + 1024 wxl slots ----
#pragma unroll
  for (int p = 0; p < 8; ++p) {
    const int s = p * 256 + tid;
    const int l = s & 63, f = s >> 6;          // f = (g*4+ut)*2+kc2
    const int g = f >> 3, ut = (f >> 1) & 3, kc2 = f & 1;
    const float sg = (g == 2) ? TLOG2E : NLOG2E;
    const int md = l & 15, qd = l >> 4;
    const float* wr = W_hh + (g * 64 + ut * 16 + md) * 64 + kc2 * 32 + qd * 4;
    uint2v w0 = cvt4(wr, sg);        // k-chunk 2*kc2,   j=0..3
    uint2v w1 = cvt4(wr + 16, sg);   // k-chunk 2*kc2+1, j=0..3
    uint4v u = {w0.x, w0.y, w1.x, w1.y};
    whl[f][l] = __builtin_bit_cast(short8, u);
  }
#pragma unroll
  for (int p = 0; p < 4; ++p) {
    const int s = p * 256 + tid;
    const int l = s & 63, f = s >> 6;          // f = g*4+ut
    const int g = f >> 2, ut = f & 3;
    const float sg = (g == 2) ? TLOG2E : NLOG2E;
    const int md = l & 15, qd = l >> 4;
    const int grow = g * 64 + ut * 16 + md;
    uint2v w = {0u, 0u};
    if (qd < 2) {
      w = cvt4(W_ih + grow * 8 + qd * 4, sg);              // x columns
    } else if (qd == 2) {
      w.x = (unsigned)(unsigned short)f2bf(sg * (b_ih[grow] + b_hh[grow]));
    }
    wxl[f][l] = __builtin_bit_cast(short4v, w);
  }
  __syncthreads();   // the ONLY barrier

  // ---- x pointer: lane (q<2, m16) loads 16B of seq m16's x per t ----
  const int seq = blk * 64 + wave * 16 + m16;
  const int bidx = seq / N_;
  const int nidx = seq - bidx * N_;
  const float* xptr = x + ((size_t)(bidx * T_) * N_ + nidx) * 8 + q * 4;
  const size_t xstride = (size_t)N_ * 8;

  floatx4 cx = {0.0f, 0.0f, 0.0f, 0.0f};
  if (q < 2) cx = *(const floatx4*)xptr;

  const floatx4 zacc = {0.0f, 0.0f, 0.0f, 0.0f};
  short4v hA[4];   // h B-frags, k-chunk = ut
#pragma unroll
  for (int kc = 0; kc < 4; ++kc) hA[kc] = mk4(0u, 0u);

  float cst[4][4];
#pragma unroll
  for (int ut = 0; ut < 4; ++ut)
#pragma unroll
    for (int r = 0; r < 4; ++r) cst[ut][r] = 0.0f;

  // Laundered weight-table pointers: redefined by empty asm each iteration
  // so the 48 fragment loads can never be hoisted out of the t-loop.
  const short8(*whp)[64] = whl;
  const short4v(*wxp)[64] = wxl;

#pragma unroll 2
  for (int t = 0; t < T_; ++t) {
    asm("" : "+v"(whp), "+v"(wxp));   // optimization barrier: zero cost
    // B x-chunk: q0/q1 = x bf16, q2 = {1.0,0,0,0} (bias col), q3 = 0
    uint2v xw = {pk_bf16(cx[0], cx[1]), pk_bf16(cx[2], cx[3])};
    if (q == 2) xw.x = 0x00003F80u;            // q>=2: cx==0 -> rest zero
    const short4v xB = __builtin_bit_cast(short4v, xw);
    // prefetch next t's x (hidden under this t's compute)
    floatx4 nx = {0.0f, 0.0f, 0.0f, 0.0f};
    if (t + 1 < T_ && q < 2)
      nx = *(const floatx4*)(xptr + (size_t)(t + 1) * xstride);

    short4v hN[4];
#pragma unroll
    for (int ut = 0; ut < 4; ++ut) {
      floatx4 acc[4];
#pragma unroll
      for (int g = 0; g < 4; ++g) {
        const short8 pA = whp[(g * 4 + ut) * 2 + 0][lane];
        const short8 pB = whp[(g * 4 + ut) * 2 + 1][lane];
        const short4v ax = wxp[g * 4 + ut][lane];
        floatx4 c = mfma16(lo4(pA), hA[0], zacc);
        c = mfma16(hi4(pA), hA[1], c);
        c = mfma16(lo4(pB), hA[2], c);
        c = mfma16(hi4(pB), hA[3], c);
        c = mfma16(ax, xB, c);
        acc[g] = c;
      }
      float hv[4];
#pragma unroll
      for (int r = 0; r < 4; ++r) {
        float di = 1.0f + __builtin_amdgcn_exp2f(acc[0][r]);
        float df = 1.0f + __builtin_amdgcn_exp2f(acc[1][r]);
        float dg = 1.0f + __builtin_amdgcn_exp2f(acc[2][r]);
        float dq = 1.0f + __builtin_amdgcn_exp2f(acc[3][r]);
        float pa = di * df, pb = dg * dq;
        float rp = __builtin_amdgcn_rcpf(pa * pb);
        float fv = rp * di * pb;                       // f = 1/df
        float ov = rp * pa * dg;                       // o = 1/dq
        float tg = fmaf(TLOG2E, dg, N2LOG2E);          // (dg-2)*2log2e
        float ig = tg * rp * (df * dq);                // i*g*2log2e
        float cs = fmaf(fv, cst[ut][r], ig);           // c*2log2e
        cst[ut][r] = cs;
        float dt = 1.0f + __builtin_amdgcn_exp2f(cs);
        float tc = fmaf(-2.0f, __builtin_amdgcn_rcpf(dt), 1.0f);  // tanh(c)
        hv[r] = ov * tc;
      }
      // D pairs ARE next-t B-frag chunk ut: {(hv0,hv1),(hv2,hv3)}
      hN[ut] = mk4(pk_bf16(hv[0], hv[1]), pk_bf16(hv[2], hv[3]));
    }
#pragma unroll
    for (int kc = 0; kc < 4; ++kc) hA[kc] = hN[kc];
    cx = nx;
  }

  // ---- final FC: y = h_T @ W_fc^T + b_fc; h_T = hA, in registers ----
  {
    floatx4 acc = zacc;
#pragma unroll
    for (int kc = 0; kc < 4; ++kc) {
      short4v fa = mk4(0u, 0u);
      if (m16 < 8) {
        uint2v w = cvt4(W_fc + m16 * 64 + kc * 16 + q * 4, 1.0f);
        fa = __builtin_bit_cast(short4v, w);
      }
      acc = mfma16(fa, hA[kc], acc);
    }
    if (q < 2) {
      const int orow = blk * 64 + wave * 16 + m16;
#pragma unroll
      for (int r = 0; r < 4; ++r)
        out[orow * 8 + q * 4 + r] = acc[r] + b_fc[q * 4 + r];
    }
  }
}

extern "C" void kernel_launch(void* const* d_in, const int* in_sizes, int n_in,
                              void* d_out, int out_size, void* d_ws,
                              size_t ws_size, hipStream_t stream) {
  const float* x    = (const float*)d_in[0];
  const float* W_ih = (const float*)d_in[1];
  const float* W_hh = (const float*)d_in[2];
  const float* b_ih = (const float*)d_in[3];
  const float* b_hh = (const float*)d_in[4];
  const float* W_fc = (const float*)d_in[5];
  const float* b_fc = (const float*)d_in[6];
  float* out = (float*)d_out;
  hipLaunchKernelGGL(lstm_kernel, dim3(NBLK), dim3(256), 0, stream,
                     x, W_ih, W_hh, b_ih, b_hh, W_fc, b_fc, out);
}

// Round 7
// 172.377 us; speedup vs baseline: 2.5116x; 1.2262x over previous
//
#include <hip/hip_runtime.h>

#define T_ 12
#define N_ 1370
#define MSEQ 32      // sequences per block
#define LDA 72       // h LDS row stride in shorts (144B -> 2-way banks max)
#define LDX 20       // x LDS row stride in shorts (40B -> conflict-free b128)
#define NBLK 2740    // 87680 / 32

typedef __attribute__((ext_vector_type(8))) short short8;
typedef __attribute__((ext_vector_type(4))) float floatx4;

#define NLOG2E -1.4426950408889634f
#define TLOG2E 2.8853900817779268f
#define N2LOG2E -5.7707801635558536f   // -2*TLOG2E

__device__ __forceinline__ short f2bf(float x) {
  unsigned u = __builtin_bit_cast(unsigned, x);
  u = (u + 0x7fffu + ((u >> 16) & 1u)) >> 16;
  return (short)u;
}
// HW packed f32->bf16: low16 = bf16(a), high16 = bf16(b)
__device__ __forceinline__ unsigned pk_bf16(float a, float b) {
  unsigned r;
  asm("v_cvt_pk_bf16_f32 %0, %1, %2" : "=v"(r) : "v"(a), "v"(b));
  return r;
}
__device__ __forceinline__ short8 load_w8s(const float* __restrict__ p, float s) {
  short8 r;
#pragma unroll
  for (int j = 0; j < 8; ++j) r[j] = f2bf(p[j] * s);
  return r;
}

// R0 structure (proven 111us / absmax 1.95e-3) with the t-body re-phased:
//   phase 1: all LDS reads (both nt)      -> b0/b1/bx arrays
//   phase 2: all 24 MFMAs                 -> materialized acc[2][4]
//   phase 3: all 8 (nt,r) activation groups batched (32 indep exp2 upfront)
//   phase 4: packs + h writes + barrier
// plus launch_bounds(256,3) (VGPR cap ~170 vs R0's (256,4)=128, where the
// scheduler folded to 52 VGPRs and serialized the trans-latency chains).
// Theory: the 110us plateau = exposed trans latency from per-tile
// MFMA->act interleave at minimal pressure; batching + budget fixes it.
// Numerics identical to R0: weights pre-scaled (i,f,o by -log2e, g by
// 2*log2e), grouped reciprocal, cell state pre-scaled by 2*log2e.
__global__ void __launch_bounds__(256, 3) lstm_kernel(
    const float* __restrict__ x, const float* __restrict__ W_ih,
    const float* __restrict__ W_hh, const float* __restrict__ b_ih,
    const float* __restrict__ b_hh, const float* __restrict__ W_fc,
    const float* __restrict__ b_fc, float* __restrict__ out) {
  __shared__ short hbuf[2][MSEQ][LDA];
  __shared__ short xls[T_][MSEQ][LDX];

  const int tid = threadIdx.x;
  const int wave = tid >> 6;
  const int lane = tid & 63;
  const int m16 = lane & 15;
  const int q = lane >> 4;
  const int blk = blockIdx.x;

  // ---- A-operand weight fragments: lane row = unit wave*16+m16 ----
  const int urow = wave * 16 + m16;
  short8 wA[4][3];
#pragma unroll
  for (int g = 0; g < 4; ++g) {
    const float sg = (g == 2) ? TLOG2E : NLOG2E;
    const int grow = g * 64 + urow;
    const float* wr = W_hh + grow * 64;
    wA[g][0] = load_w8s(wr + q * 8, sg);
    wA[g][1] = load_w8s(wr + 32 + q * 8, sg);
    short8 z = {0, 0, 0, 0, 0, 0, 0, 0};
    if (q == 0) {
      wA[g][2] = load_w8s(W_ih + grow * 8, sg);  // k=64..71: x columns
    } else if (q == 1) {
      z[0] = f2bf(sg * (b_ih[grow] + b_hh[grow]));  // k=72: bias column
      wA[g][2] = z;
    } else {
      wA[g][2] = z;  // k=80..95 dead
    }
  }

  // ---- zero LDS (h0 = 0, pads = 0) ----
  {
    int* hp = (int*)hbuf;
#pragma unroll
    for (int i = tid; i < (2 * MSEQ * LDA) / 2; i += 256) hp[i] = 0;
    int* xp = (int*)xls;
#pragma unroll
    for (int i = tid; i < (T_ * MSEQ * LDX) / 2; i += 256) xp[i] = 0;
  }
  __syncthreads();

  // ---- stage all 12 timesteps of x as bf16 + the 1.0 bias column ----
  {
    const int xseq = tid >> 3, xc = tid & 7;
    const int s0 = blk * MSEQ + xseq;
    const int bidx = s0 / N_;
    const int nidx = s0 - bidx * N_;
    const float* xp = x + ((size_t)(bidx * T_) * N_ + nidx) * 8 + xc;
#pragma unroll
    for (int t = 0; t < T_; ++t) {
      xls[t][xseq][xc] = f2bf(xp[(size_t)t * (N_ * 8)]);
      if (xc == 0) xls[t][xseq][8] = (short)0x3F80;  // bf16 1.0
    }
  }
  __syncthreads();

  const int xoff = q ? 8 : 0;  // q>=1 lanes read the 1.0 column region
  const floatx4 zacc = {0.0f, 0.0f, 0.0f, 0.0f};

  float cst[2][4];
#pragma unroll
  for (int nt = 0; nt < 2; ++nt)
#pragma unroll
    for (int r = 0; r < 4; ++r) cst[nt][r] = 0.0f;

  for (int t = 0; t < T_; ++t) {
    const int rb = t & 1, wb = rb ^ 1;

    // ---- phase 1: all LDS reads ----
    short8 b0[2], b1[2], bx[2];
#pragma unroll
    for (int nt = 0; nt < 2; ++nt) {
      const int srow = nt * 16 + m16;
      b0[nt] = *(const short8*)&hbuf[rb][srow][q * 8];
      b1[nt] = *(const short8*)&hbuf[rb][srow][32 + q * 8];
      bx[nt] = *(const short8*)&xls[t][srow][xoff];
    }

    // ---- phase 2: all 24 MFMAs into materialized accumulators ----
    floatx4 acc[2][4];
#pragma unroll
    for (int nt = 0; nt < 2; ++nt)
#pragma unroll
      for (int g = 0; g < 4; ++g) {
        floatx4 c = __builtin_amdgcn_mfma_f32_16x16x32_bf16(wA[g][0], b0[nt], zacc, 0, 0, 0);
        c = __builtin_amdgcn_mfma_f32_16x16x32_bf16(wA[g][1], b1[nt], c, 0, 0, 0);
        c = __builtin_amdgcn_mfma_f32_16x16x32_bf16(wA[g][2], bx[nt], c, 0, 0, 0);
        acc[nt][g] = c;
      }

    // ---- phase 3: batched activation, 8 independent (nt,r) groups.
    // Launch all 32 gate exp2s first so the trans pipe streams; the
    // dependent chains of the 8 groups then interleave. ----
    float di[2][4], df[2][4], dg_[2][4], dq_[2][4];
#pragma unroll
    for (int nt = 0; nt < 2; ++nt)
#pragma unroll
      for (int r = 0; r < 4; ++r) {
        di[nt][r] = 1.0f + __builtin_amdgcn_exp2f(acc[nt][0][r]);
        df[nt][r] = 1.0f + __builtin_amdgcn_exp2f(acc[nt][1][r]);
        dg_[nt][r] = 1.0f + __builtin_amdgcn_exp2f(acc[nt][2][r]);
        dq_[nt][r] = 1.0f + __builtin_amdgcn_exp2f(acc[nt][3][r]);
      }
    unsigned long long pkv[2];
#pragma unroll
    for (int nt = 0; nt < 2; ++nt) {
      float hv[4];
#pragma unroll
      for (int r = 0; r < 4; ++r) {
        float pa = di[nt][r] * df[nt][r], pb = dg_[nt][r] * dq_[nt][r];
        float rp = __builtin_amdgcn_rcpf(pa * pb);
        float fv = rp * di[nt][r] * pb;                 // f = 1/df
        float ov = rp * pa * dg_[nt][r];                // o = 1/dq
        float tg = fmaf(TLOG2E, dg_[nt][r], N2LOG2E);   // (dg-2)*2log2e
        float ig = tg * rp * (df[nt][r] * dq_[nt][r]);  // i*g*2log2e
        float cs = fmaf(fv, cst[nt][r], ig);            // c*2log2e
        cst[nt][r] = cs;
        float dt = 1.0f + __builtin_amdgcn_exp2f(cs);
        float tc = fmaf(-2.0f, __builtin_amdgcn_rcpf(dt), 1.0f);  // tanh(c)
        hv[r] = ov * tc;
      }
      pkv[nt] = (unsigned long long)pk_bf16(hv[0], hv[1]) |
                ((unsigned long long)pk_bf16(hv[2], hv[3]) << 32);
    }

    // ---- phase 4: h writes + barrier ----
#pragma unroll
    for (int nt = 0; nt < 2; ++nt) {
      const int srow = nt * 16 + m16;
      *(unsigned long long*)&hbuf[wb][srow][wave * 16 + q * 4] = pkv[nt];
    }
    __syncthreads();
  }

  // ---- final FC: y = h_T @ W_fc^T + b_fc; h_T is in hbuf[0] ----
  if (wave < 2) {
    short8 f0, f1;
    short8 z = {0, 0, 0, 0, 0, 0, 0, 0};
    if (m16 < 8) {
      const float* wr = W_fc + m16 * 64;
      f0 = load_w8s(wr + q * 8, 1.0f);
      f1 = load_w8s(wr + 32 + q * 8, 1.0f);
    } else {
      f0 = z;
      f1 = z;
    }
    const int srow = wave * 16 + m16;
    short8 h0 = *(const short8*)&hbuf[0][srow][q * 8];
    short8 h1 = *(const short8*)&hbuf[0][srow][32 + q * 8];
    floatx4 acc = __builtin_amdgcn_mfma_f32_16x16x32_bf16(f0, h0, zacc, 0, 0, 0);
    acc = __builtin_amdgcn_mfma_f32_16x16x32_bf16(f1, h1, acc, 0, 0, 0);
    if (q < 2) {
      const int orow = blk * MSEQ + srow;
#pragma unroll
      for (int r = 0; r < 4; ++r)
        out[orow * 8 + q * 4 + r] = acc[r] + b_fc[q * 4 + r];
    }
  }
}

extern "C" void kernel_launch(void* const* d_in, const int* in_sizes, int n_in,
                              void* d_out, int out_size, void* d_ws,
                              size_t ws_size, hipStream_t stream) {
  const float* x    = (const float*)d_in[0];
  const float* W_ih = (const float*)d_in[1];
  const float* W_hh = (const float*)d_in[2];
  const float* b_ih = (const float*)d_in[3];
  const float* b_hh = (const float*)d_in[4];
  const float* W_fc = (const float*)d_in[5];
  const float* b_fc = (const float*)d_in[6];
  float* out = (float*)d_out;
  hipLaunchKernelGGL(lstm_kernel, dim3(NBLK), dim3(256), 0, stream,
                     x, W_ih, W_hh, b_ih, b_hh, W_fc, b_fc, out);
}

// Round 8
// 169.144 us; speedup vs baseline: 2.5597x; 1.0191x over previous
//
#include <hip/hip_runtime.h>

#define T_ 12
#define N_ 1370
#define MSEQ 32      // sequences per block
#define LDA 72       // h LDS row stride in shorts (144B -> 2-way banks max)
#define LDX 20       // x LDS row stride in shorts (40B -> conflict-free b128)
#define NBLK 2740    // 87680 / 32

typedef __attribute__((ext_vector_type(8))) short short8;
typedef __attribute__((ext_vector_type(4))) float floatx4;

#define NLOG2E -1.4426950408889634f
#define TLOG2E 2.8853900817779268f
#define N2LOG2E -5.7707801635558536f   // -2*TLOG2E

__device__ __forceinline__ short f2bf(float x) {
  unsigned u = __builtin_bit_cast(unsigned, x);
  u = (u + 0x7fffu + ((u >> 16) & 1u)) >> 16;
  return (short)u;
}
// HW packed f32->bf16: low16 = bf16(a), high16 = bf16(b)
__device__ __forceinline__ unsigned pk_bf16(float a, float b) {
  unsigned r;
  asm("v_cvt_pk_bf16_f32 %0, %1, %2" : "=v"(r) : "v"(a), "v"(b));
  return r;
}
__device__ __forceinline__ short8 load_w8s(const float* __restrict__ p, float s) {
  short8 r;
#pragma unroll
  for (int j = 0; j < 8; ++j) r[j] = f2bf(p[j] * s);
  return r;
}

// R0/R7 structure (proven 110us, absmax 1.95e-3) with transcendental-op
// reduction in the activation. Model: 4 structurally different schedules
// all hit ~110us @ VALUBusy ~57% -> op-bound on the trans pipe
// (exp2/rcp ~16cyc/wave64 -> 73% of VALU-pipe time). This round cuts rcp
// count 16 -> 6 per lane-t via exact grouped reciprocals:
//   - rp (4-gate shared denominator) grouped across the nt pair per r:
//     R = rcp(PA*PB); rpA = R*PB; rpB = R*PA.
//   - tanh-denominator rcp grouped across the 4 r cells per nt:
//     R = rcp(d0*d1*d2*d3); prefix/suffix products extract each 1/di.
// Extra muls are exact-rounded f32; rcp itself is the same HW op, so
// accuracy is unchanged at bf16 scale (absmax stays 1.95e-3).
// Weights pre-scaled: i,f,o rows by -log2e, g rows by 2*log2e; cell state
// carried pre-scaled by 2*log2e (numerics proven R0-R7).
__global__ void __launch_bounds__(256, 3) lstm_kernel(
    const float* __restrict__ x, const float* __restrict__ W_ih,
    const float* __restrict__ W_hh, const float* __restrict__ b_ih,
    const float* __restrict__ b_hh, const float* __restrict__ W_fc,
    const float* __restrict__ b_fc, float* __restrict__ out) {
  __shared__ short hbuf[2][MSEQ][LDA];
  __shared__ short xls[T_][MSEQ][LDX];

  const int tid = threadIdx.x;
  const int wave = tid >> 6;
  const int lane = tid & 63;
  const int m16 = lane & 15;
  const int q = lane >> 4;
  const int blk = blockIdx.x;

  // ---- A-operand weight fragments: lane row = unit wave*16+m16 ----
  const int urow = wave * 16 + m16;
  short8 wA[4][3];
#pragma unroll
  for (int g = 0; g < 4; ++g) {
    const float sg = (g == 2) ? TLOG2E : NLOG2E;
    const int grow = g * 64 + urow;
    const float* wr = W_hh + grow * 64;
    wA[g][0] = load_w8s(wr + q * 8, sg);
    wA[g][1] = load_w8s(wr + 32 + q * 8, sg);
    short8 z = {0, 0, 0, 0, 0, 0, 0, 0};
    if (q == 0) {
      wA[g][2] = load_w8s(W_ih + grow * 8, sg);  // k=64..71: x columns
    } else if (q == 1) {
      z[0] = f2bf(sg * (b_ih[grow] + b_hh[grow]));  // k=72: bias column
      wA[g][2] = z;
    } else {
      wA[g][2] = z;  // k=80..95 dead
    }
  }

  // ---- zero LDS (h0 = 0, pads = 0) ----
  {
    int* hp = (int*)hbuf;
#pragma unroll
    for (int i = tid; i < (2 * MSEQ * LDA) / 2; i += 256) hp[i] = 0;
    int* xp = (int*)xls;
#pragma unroll
    for (int i = tid; i < (T_ * MSEQ * LDX) / 2; i += 256) xp[i] = 0;
  }
  __syncthreads();

  // ---- stage all 12 timesteps of x as bf16 + the 1.0 bias column ----
  {
    const int xseq = tid >> 3, xc = tid & 7;
    const int s0 = blk * MSEQ + xseq;
    const int bidx = s0 / N_;
    const int nidx = s0 - bidx * N_;
    const float* xp = x + ((size_t)(bidx * T_) * N_ + nidx) * 8 + xc;
#pragma unroll
    for (int t = 0; t < T_; ++t) {
      xls[t][xseq][xc] = f2bf(xp[(size_t)t * (N_ * 8)]);
      if (xc == 0) xls[t][xseq][8] = (short)0x3F80;  // bf16 1.0
    }
  }
  __syncthreads();

  const int xoff = q ? 8 : 0;  // q>=1 lanes read the 1.0 column region
  const floatx4 zacc = {0.0f, 0.0f, 0.0f, 0.0f};

  float cst[2][4];
#pragma unroll
  for (int nt = 0; nt < 2; ++nt)
#pragma unroll
    for (int r = 0; r < 4; ++r) cst[nt][r] = 0.0f;

  for (int t = 0; t < T_; ++t) {
    const int rb = t & 1, wb = rb ^ 1;

    // ---- phase 1: all LDS reads ----
    short8 b0[2], b1[2], bx[2];
#pragma unroll
    for (int nt = 0; nt < 2; ++nt) {
      const int srow = nt * 16 + m16;
      b0[nt] = *(const short8*)&hbuf[rb][srow][q * 8];
      b1[nt] = *(const short8*)&hbuf[rb][srow][32 + q * 8];
      bx[nt] = *(const short8*)&xls[t][srow][xoff];
    }

    // ---- phase 2: all 24 MFMAs into materialized accumulators ----
    floatx4 acc[2][4];
#pragma unroll
    for (int nt = 0; nt < 2; ++nt)
#pragma unroll
      for (int g = 0; g < 4; ++g) {
        floatx4 c = __builtin_amdgcn_mfma_f32_16x16x32_bf16(wA[g][0], b0[nt], zacc, 0, 0, 0);
        c = __builtin_amdgcn_mfma_f32_16x16x32_bf16(wA[g][1], b1[nt], c, 0, 0, 0);
        c = __builtin_amdgcn_mfma_f32_16x16x32_bf16(wA[g][2], bx[nt], c, 0, 0, 0);
        acc[nt][g] = c;
      }

    // ---- phase 3a: all 32 gate exp2 (independent, stream the trans pipe)
    float di[2][4], df[2][4], dgv[2][4], dqv[2][4];
#pragma unroll
    for (int nt = 0; nt < 2; ++nt)
#pragma unroll
      for (int r = 0; r < 4; ++r) {
        di[nt][r] = 1.0f + __builtin_amdgcn_exp2f(acc[nt][0][r]);
        df[nt][r] = 1.0f + __builtin_amdgcn_exp2f(acc[nt][1][r]);
        dgv[nt][r] = 1.0f + __builtin_amdgcn_exp2f(acc[nt][2][r]);
        dqv[nt][r] = 1.0f + __builtin_amdgcn_exp2f(acc[nt][3][r]);
      }

    // ---- phase 3b: grouped rp across the nt pair (4 rcp instead of 8)
    float pa[2][4], pb[2][4], rp[2][4];
#pragma unroll
    for (int r = 0; r < 4; ++r) {
      pa[0][r] = di[0][r] * df[0][r];
      pb[0][r] = dgv[0][r] * dqv[0][r];
      pa[1][r] = di[1][r] * df[1][r];
      pb[1][r] = dgv[1][r] * dqv[1][r];
      const float PA = pa[0][r] * pb[0][r];
      const float PB = pa[1][r] * pb[1][r];
      const float R = __builtin_amdgcn_rcpf(PA * PB);
      rp[0][r] = R * PB;
      rp[1][r] = R * PA;
    }

    // ---- phase 3c: gate algebra + cell update + tanh-denominator exp2
    float ov[2][4], dt[2][4];
#pragma unroll
    for (int nt = 0; nt < 2; ++nt)
#pragma unroll
      for (int r = 0; r < 4; ++r) {
        const float fv = rp[nt][r] * di[nt][r] * pb[nt][r];      // f = 1/df
        ov[nt][r] = rp[nt][r] * pa[nt][r] * dgv[nt][r];          // o = 1/dq
        const float tg = fmaf(TLOG2E, dgv[nt][r], N2LOG2E);      // (dg-2)*2log2e
        const float ig = tg * rp[nt][r] * (df[nt][r] * dqv[nt][r]);
        const float cs = fmaf(fv, cst[nt][r], ig);               // c*2log2e
        cst[nt][r] = cs;
        dt[nt][r] = 1.0f + __builtin_amdgcn_exp2f(cs);
      }

    // ---- phase 3d: grouped tanh reciprocal per nt (1 rcp for 4 cells)
    unsigned long long pkv[2];
#pragma unroll
    for (int nt = 0; nt < 2; ++nt) {
      const float m01 = dt[nt][0] * dt[nt][1];
      const float m23 = dt[nt][2] * dt[nt][3];
      const float R = __builtin_amdgcn_rcpf(m01 * m23);
      const float r01 = R * m23, r23 = R * m01;
      float rdt[4];
      rdt[0] = r01 * dt[nt][1];
      rdt[1] = r01 * dt[nt][0];
      rdt[2] = r23 * dt[nt][3];
      rdt[3] = r23 * dt[nt][2];
      float hv[4];
#pragma unroll
      for (int r = 0; r < 4; ++r) {
        const float tw = ov[nt][r] + ov[nt][r];                  // 2*o
        hv[r] = fmaf(-tw, rdt[r], ov[nt][r]);                    // o*(1-2/dt)
      }
      pkv[nt] = (unsigned long long)pk_bf16(hv[0], hv[1]) |
                ((unsigned long long)pk_bf16(hv[2], hv[3]) << 32);
    }

    // ---- phase 4: h writes + barrier ----
#pragma unroll
    for (int nt = 0; nt < 2; ++nt) {
      const int srow = nt * 16 + m16;
      *(unsigned long long*)&hbuf[wb][srow][wave * 16 + q * 4] = pkv[nt];
    }
    __syncthreads();
  }

  // ---- final FC: y = h_T @ W_fc^T + b_fc; h_T is in hbuf[0] ----
  if (wave < 2) {
    short8 f0, f1;
    short8 z = {0, 0, 0, 0, 0, 0, 0, 0};
    if (m16 < 8) {
      const float* wr = W_fc + m16 * 64;
      f0 = load_w8s(wr + q * 8, 1.0f);
      f1 = load_w8s(wr + 32 + q * 8, 1.0f);
    } else {
      f0 = z;
      f1 = z;
    }
    const int srow = wave * 16 + m16;
    short8 h0 = *(const short8*)&hbuf[0][srow][q * 8];
    short8 h1 = *(const short8*)&hbuf[0][srow][32 + q * 8];
    floatx4 acc = __builtin_amdgcn_mfma_f32_16x16x32_bf16(f0, h0, zacc, 0, 0, 0);
    acc = __builtin_amdgcn_mfma_f32_16x16x32_bf16(f1, h1, acc, 0, 0, 0);
    if (q < 2) {
      const int orow = blk * MSEQ + srow;
#pragma unroll
      for (int r = 0; r < 4; ++r)
        out[orow * 8 + q * 4 + r] = acc[r] + b_fc[q * 4 + r];
    }
  }
}

extern "C" void kernel_launch(void* const* d_in, const int* in_sizes, int n_in,
                              void* d_out, int out_size, void* d_ws,
                              size_t ws_size, hipStream_t stream) {
  const float* x    = (const float*)d_in[0];
  const float* W_ih = (const float*)d_in[1];
  const float* W_hh = (const float*)d_in[2];
  const float* b_ih = (const float*)d_in[3];
  const float* b_hh = (const float*)d_in[4];
  const float* W_fc = (const float*)d_in[5];
  const float* b_fc = (const float*)d_in[6];
  float* out = (float*)d_out;
  hipLaunchKernelGGL(lstm_kernel, dim3(NBLK), dim3(256), 0, stream,
                     x, W_ih, W_hh, b_ih, b_hh, W_fc, b_fc, out);
}